// Round 1
// baseline (330.343 us; speedup 1.0000x reference)
//
#include <hip/hip_runtime.h>
#include <hip/hip_bf16.h>

#define C_ 256
#define H_ 64
#define W_ 64
#define N_ 16
#define HW_ 4096
#define IMG_ (C_ * HW_)          // 1048576 elems (fp32 image)
#define PADIMG_ (66 * 66 * 256)  // 1115136 shorts per padded NHWC image
#define WT_ELEMS_ (9 * 256 * 256)

typedef short bf16x8 __attribute__((ext_vector_type(8)));
typedef float f32x16 __attribute__((ext_vector_type(16)));

__device__ __forceinline__ unsigned short f2bf(float f) {
  __hip_bfloat16 h = __float2bfloat16(f);  // RTNE
  return *reinterpret_cast<unsigned short*>(&h);
}

__device__ __forceinline__ void gld_lds16(const void* g, void* l) {
  __builtin_amdgcn_global_load_lds(
      (const __attribute__((address_space(1))) void*)g,
      (__attribute__((address_space(3))) void*)l, 16, 0, 0);
}

// ---------------------------------------------------------------------------
// Fused x->padded-NHWC-bf16 transform + mask logits (fp64, sign-exact).
// ---------------------------------------------------------------------------
__global__ __launch_bounds__(256) void xpadmask_kernel(
    const float* __restrict__ x, const float* __restrict__ wm,
    const float* __restrict__ bm, short* __restrict__ Xp,
    unsigned char* __restrict__ mask) {
  __shared__ unsigned short lds[64 * 260];
  __shared__ float wms[256];
  __shared__ double sums[4][64];
  const int h = blockIdx.x, img = blockIdx.y;
  const int tid = threadIdx.x;
  const int wv = tid >> 6, wl = tid & 63;
  wms[tid] = wm[tid];
  __syncthreads();
  const float* xi = x + (size_t)img * IMG_ + h * 64;
  double a0 = 0.0, a1 = 0.0, a2 = 0.0, a3 = 0.0;
#pragma unroll 4
  for (int i = 0; i < 16; ++i) {
#pragma unroll
    for (int u = 0; u < 4; ++u) {
      int c = (i * 4 + u) * 4 + wv;
      float v = xi[(size_t)c * HW_ + wl];
      lds[wl * 260 + c] = f2bf(v);
      double p = (double)v * (double)wms[c];
      if (u == 0) a0 += p;
      else if (u == 1) a1 += p;
      else if (u == 2) a2 += p;
      else a3 += p;
    }
  }
  sums[wv][wl] = (a0 + a1) + (a2 + a3);
  __syncthreads();
  short* Xpi = Xp + (size_t)img * PADIMG_ + ((h + 1) * 66 + 1) * 256;
#pragma unroll
  for (int j = 0; j < 16; ++j) {
    int w = j * 4 + wv;
    int c4 = wl * 4;
    uint2 d = *(const uint2*)&lds[w * 260 + c4];
    *(uint2*)&Xpi[(size_t)w * 256 + c4] = d;
  }
  if (wv == 0) {
    double t = sums[0][wl] + sums[1][wl] + sums[2][wl] + sums[3][wl] +
               (double)bm[0];
    mask[img * HW_ + h * 64 + wl] = (t > 0.0) ? 1 : 0;
  }
}

__global__ __launch_bounds__(256) void dilate_kernel(
    const unsigned char* __restrict__ mask, unsigned char* __restrict__ md) {
  int pix = blockIdx.x * 256 + threadIdx.x;
  int n = pix >> 12;
  int hw = pix & (HW_ - 1);
  int h = hw >> 6, w = hw & 63;
  int m = 0;
  for (int dy = -1; dy <= 1; dy++) {
    int hh = h + dy;
    if (hh < 0 || hh >= H_) continue;
    for (int dx = -1; dx <= 1; dx++) {
      int ww = w + dx;
      if (ww < 0 || ww >= W_) continue;
      m |= mask[n * HW_ + hh * W_ + ww];
    }
  }
  md[pix] = (unsigned char)m;
}

// ---------------------------------------------------------------------------
// Weight transform: Wt[t][k][c] = bf16(w[k][c*9+t])   (t = r*3+s)
// ---------------------------------------------------------------------------
__global__ __launch_bounds__(256) void wt_kernel(
    const float* __restrict__ w1, const float* __restrict__ w2,
    short* __restrict__ Wt1, short* __restrict__ Wt2) {
  const int k = blockIdx.x, c = threadIdx.x;
  const float* src = blockIdx.y ? w2 : w1;
  short* dst = blockIdx.y ? Wt2 : Wt1;
  const float* s = src + ((size_t)k * 256 + c) * 9;
#pragma unroll
  for (int t = 0; t < 9; ++t)
    dst[t * 65536 + k * 256 + c] = (short)f2bf(s[t]);
}

// ---------------------------------------------------------------------------
// Zero the padded halo (rows 0,65; cols 0,65) of Xp and Hp.
// ---------------------------------------------------------------------------
__global__ __launch_bounds__(128) void halo_zero(short* __restrict__ Xp,
                                                 short* __restrict__ Hp) {
  int p = blockIdx.x;  // 0..259 halo pixel id
  int r, c;
  if (p < 66) { r = 0; c = p; }
  else if (p < 132) { r = 65; c = p - 66; }
  else if (p < 196) { r = p - 131; c = 0; }
  else { r = p - 195; c = 65; }
  short* buf = blockIdx.z ? Hp : Xp;
  unsigned int* d = (unsigned int*)(buf + (size_t)blockIdx.y * PADIMG_ +
                                    (size_t)(r * 66 + c) * 256);
  d[threadIdx.x] = 0u;
}

// ---------------------------------------------------------------------------
// Implicit-GEMM 3x3 conv, v2 (pipelined).
// Tile: 64 out-ch x 512 px (8 rows x 64 cols), 4 waves, 2 blocks/CU.
// MFMA 32x32x16 bf16, K-chunk = 16 in-ch (16 chunks), acc 2x4 f32x16.
// LDS (79104 B, double-buffered):
//   B[buf][khalf]: 660 slots (10 padded rows x 66) x 16B   (K-half split so
//   W[buf][khalf]: 9 taps x 64 ch x 16B                     frag reads are
//   16B-consecutive across lanes -> conflict-free ds_read_b128)
// Pipeline (T3-min): stage kk+1 -> compute kk -> s_waitcnt vmcnt(0); s_barrier
// (raw barrier, ONE per kk; loads land under compute; no __syncthreads drain).
// XCD swizzle: 4 out-ch sibling blocks (same B tile) share d%8 -> same L2.
// EPI 0: dstH[padded NHWC] = g ? relu(acc) : 0        (g = dilated mask)
// EPI 1: dstF[NCHW fp32]   = xres + (g ? relu(acc):0) (g = std mask)
// ---------------------------------------------------------------------------
#define BREG 5280   // shorts per B region: 660 slots * 8
#define WBASE 21120 // 4 * BREG
#define WREG 4608   // shorts per W region: 9 * 64 * 8

__device__ __forceinline__ void stage_tile(short* sm, const short* Xb,
                                           const short* Wt, int ch0, int buf,
                                           int ko, int wave, int lane) {
  short* Bd = sm + buf * 2 * BREG;
  short* Wd = sm + WBASE + buf * 2 * WREG;
  // B: 22 insts (11 per K-half; inst i<10 covers slots 64i..64i+63, inst 10
  // covers 596..659 overlapping inst 9 with identical data). Waves 2,3 dup
  // inst 21 (same bytes, same data -> benign) so all waves issue 6.
#pragma unroll
  for (int q = 0; q < 6; ++q) {
    int n = wave + 4 * q;
    if (n > 21) n = 21;
    const int h = (n >= 11) ? 1 : 0;
    const int i = n - h * 11;
    const int row0 = (i < 10) ? i * 64 : 596;
    gld_lds16(Xb + (size_t)(row0 + lane) * 256 + ko + h * 8,
              Bd + h * BREG + row0 * 8);
  }
  // W: 18 insts (tap x K-half, 64 ch rows per inst). Waves 2,3 dup inst 17.
#pragma unroll
  for (int q = 0; q < 5; ++q) {
    int n = wave + 4 * q;
    if (n > 17) n = 17;
    const int h = (n >= 9) ? 1 : 0;
    const int t = n - h * 9;
    gld_lds16(Wt + (size_t)t * 65536 + (size_t)(ch0 + lane) * 256 + ko + h * 8,
              Wd + h * WREG + t * 512);
  }
}

template <int EPI>
__global__ __launch_bounds__(256, 2) void conv_mfma(
    const short* __restrict__ src, const short* __restrict__ Wt,
    const unsigned char* __restrict__ gate, const float* __restrict__ xres,
    short* __restrict__ dstH, float* __restrict__ dstF, int swz) {
  __shared__ __align__(16) short sm[39552];  // 79104 B -> 2 blocks/CU

  const int tid = threadIdx.x;
  const int lane = tid & 63, wave = tid >> 6;
  const int ln31 = lane & 31, kh = lane >> 5;

  // Block decode; swizzled path groups the 4 ch-sibling blocks on one XCD.
  int bx, by, bz;
  {
    int d = blockIdx.x + 4 * (blockIdx.y + 8 * blockIdx.z);
    if (swz) {
      int k = d & 7, j = d >> 3;
      bx = j & 3;
      by = (j >> 2) & 7;
      bz = ((j >> 5) << 3) + k;
    } else {
      bx = blockIdx.x;
      by = blockIdx.y;
      bz = blockIdx.z;
    }
  }
  const int ch0 = bx * 64;
  const int h0 = by * 8;
  const int img = bz;

  const short* Xb = src + (size_t)img * PADIMG_ + (size_t)(h0 * 66) * 256;

  f32x16 acc[2][4];
#pragma unroll
  for (int i = 0; i < 2; ++i)
#pragma unroll
    for (int j = 0; j < 4; ++j)
#pragma unroll
      for (int e = 0; e < 16; ++e) acc[i][j][e] = 0.f;

  stage_tile(sm, Xb, Wt, ch0, 0, 0, wave, lane);
  asm volatile("s_waitcnt vmcnt(0)\n\ts_barrier" ::: "memory");

#pragma unroll 2
  for (int kk = 0; kk < 16; ++kk) {
    const int cur = kk & 1;
    if (kk < 15) stage_tile(sm, Xb, Wt, ch0, cur ^ 1, (kk + 1) * 16, wave, lane);

    // Per-thread LDS bases: all frag reads become base + compile-time offset.
    const short* Bth = sm + (cur * 2 + kh) * BREG + (wave * 132 + ln31) * 8;
    const short* Wth = sm + WBASE + (cur * 2 + kh) * WREG + ln31 * 8;
#pragma unroll
    for (int t = 0; t < 9; ++t) {
      const int dy = t / 3, dx = t % 3;
      bf16x8 a0 = *(const bf16x8*)(Wth + t * 512);        // ch rows 0..31
      bf16x8 a1 = *(const bf16x8*)(Wth + t * 512 + 256);  // ch rows 32..63
      bf16x8 b[4];
#pragma unroll
      for (int j = 0; j < 4; ++j) {
        const int off = (((j >> 1) + dy) * 66 + (j & 1) * 32 + dx) * 8;
        b[j] = *(const bf16x8*)(Bth + off);
      }
#pragma unroll
      for (int j = 0; j < 4; ++j) {
        acc[0][j] = __builtin_amdgcn_mfma_f32_32x32x16_bf16(a0, b[j],
                                                            acc[0][j], 0, 0, 0);
        acc[1][j] = __builtin_amdgcn_mfma_f32_32x32x16_bf16(a1, b[j],
                                                            acc[1][j], 0, 0, 0);
      }
    }
    if (kk < 15)
      asm volatile("s_waitcnt vmcnt(0)\n\ts_barrier" ::: "memory");
  }

  // Epilogue. 32x32 D layout: col(pixel)=lane&31, row(ch)=(reg&3)+8*(reg>>2)
  // +4*(lane>>5)  => reg group rg gives 4 consecutive channels.
  const int rb = h0 + wave * 2;
#pragma unroll
  for (int j = 0; j < 4; ++j) {
    const int r = rb + (j >> 1);
    const int col = (j & 1) * 32 + ln31;
    const int pidx = r * 64 + col;
    const unsigned char g = gate[img * HW_ + pidx];
#pragma unroll
    for (int i = 0; i < 2; ++i) {
      const f32x16 v = acc[i][j];
#pragma unroll
      for (int rg = 0; rg < 4; ++rg) {
        const int ch = ch0 + i * 32 + rg * 8 + kh * 4;
        float e0 = g ? fmaxf(v[rg * 4 + 0], 0.f) : 0.f;
        float e1 = g ? fmaxf(v[rg * 4 + 1], 0.f) : 0.f;
        float e2 = g ? fmaxf(v[rg * 4 + 2], 0.f) : 0.f;
        float e3 = g ? fmaxf(v[rg * 4 + 3], 0.f) : 0.f;
        if (EPI == 0) {
          uint2 u;
          u.x = (unsigned int)f2bf(e0) | ((unsigned int)f2bf(e1) << 16);
          u.y = (unsigned int)f2bf(e2) | ((unsigned int)f2bf(e3) << 16);
          short* dp = dstH + (size_t)img * PADIMG_ +
                      ((size_t)((r + 1) * 66 + (col + 1))) * 256 + ch;
          *(uint2*)dp = u;
        } else {
          size_t o = (size_t)img * IMG_ + (size_t)ch * HW_ + pidx;
          dstF[o] = xres[o] + e0;
          dstF[o + HW_] = xres[o + HW_] + e1;
          dstF[o + 2 * HW_] = xres[o + 2 * HW_] + e2;
          dstF[o + 3 * HW_] = xres[o + 3 * HW_] + e3;
        }
      }
    }
  }
}

// ---------------------------------------------------------------------------
extern "C" void kernel_launch(void* const* d_in, const int* in_sizes, int n_in,
                              void* d_out, int out_size, void* d_ws,
                              size_t ws_size, hipStream_t stream) {
  const float* x = (const float*)d_in[0];
  const float* w1 = (const float*)d_in[1];
  const float* w2 = (const float*)d_in[2];
  const float* wmask = (const float*)d_in[3];
  const float* bmask = (const float*)d_in[4];
  float* out = (float*)d_out;

  char* ws = (char*)d_ws;
  unsigned char* mask = (unsigned char*)ws;          // 64 KB
  unsigned char* md = (unsigned char*)(ws + 65536);  // 64 KB
  short* Wt1 = (short*)(ws + 131072);                // 1.125 MiB
  short* Wt2 = Wt1 + WT_ELEMS_;                      // 1.125 MiB
  short* Xp = (short*)(ws + 2490368);

  const size_t fixed = 2490368;
  const size_t tailpad = 32768;  // safety pad past last image
  const size_t per_img = 2 * (size_t)PADIMG_ * 2;  // Xp + Hp bytes per image
  int B = (ws_size > fixed + tailpad)
              ? (int)((ws_size - fixed - tailpad) / per_img) : 0;
  if (B > N_) B = N_;
  if (B < 1) B = 1;
  short* Hp = Xp + (size_t)B * PADIMG_;

  wt_kernel<<<dim3(256, 2), 256, 0, stream>>>(w1, w2, Wt1, Wt2);
  halo_zero<<<dim3(260, B, 2), 128, 0, stream>>>(Xp, Hp);

  for (int n0 = 0; n0 < N_; n0 += B) {
    const int nb = (N_ - n0 < B) ? (N_ - n0) : B;
    const int swz = (nb % 8 == 0) ? 1 : 0;
    xpadmask_kernel<<<dim3(64, nb), 256, 0, stream>>>(
        x + (size_t)n0 * IMG_, wmask, bmask, Xp, mask + n0 * HW_);
    dilate_kernel<<<nb * HW_ / 256, 256, 0, stream>>>(mask + n0 * HW_,
                                                      md + n0 * HW_);
    conv_mfma<0><<<dim3(4, 8, nb), 256, 0, stream>>>(
        Xp, Wt1, md + n0 * HW_, nullptr, Hp, nullptr, swz);
    conv_mfma<1><<<dim3(4, 8, nb), 256, 0, stream>>>(
        Hp, Wt2, mask + n0 * HW_, x + (size_t)n0 * IMG_, nullptr,
        out + (size_t)n0 * IMG_, swz);
  }
}

// Round 2
// 299.726 us; speedup vs baseline: 1.1021x; 1.1021x over previous
//
#include <hip/hip_runtime.h>
#include <hip/hip_bf16.h>

#define C_ 256
#define H_ 64
#define W_ 64
#define N_ 16
#define HW_ 4096
#define IMG_ (C_ * HW_)          // 1048576 elems (fp32 image)
#define PADIMG_ (66 * 66 * 256)  // 1115136 shorts per padded NHWC image
#define WT_ELEMS_ (9 * 256 * 256)

typedef short bf16x8 __attribute__((ext_vector_type(8)));
typedef float f32x16 __attribute__((ext_vector_type(16)));

__device__ __forceinline__ unsigned short f2bf(float f) {
  __hip_bfloat16 h = __float2bfloat16(f);  // RTNE
  return *reinterpret_cast<unsigned short*>(&h);
}

__device__ __forceinline__ void gld_lds16(const void* g, void* l) {
  __builtin_amdgcn_global_load_lds(
      (const __attribute__((address_space(1))) void*)g,
      (__attribute__((address_space(3))) void*)l, 16, 0, 0);
}

// ---------------------------------------------------------------------------
// Fused x->padded-NHWC-bf16 transform + mask logits (fp64, sign-exact).
// ---------------------------------------------------------------------------
__global__ __launch_bounds__(256) void xpadmask_kernel(
    const float* __restrict__ x, const float* __restrict__ wm,
    const float* __restrict__ bm, short* __restrict__ Xp,
    unsigned char* __restrict__ mask) {
  __shared__ unsigned short lds[64 * 260];
  __shared__ float wms[256];
  __shared__ double sums[4][64];
  const int h = blockIdx.x, img = blockIdx.y;
  const int tid = threadIdx.x;
  const int wv = tid >> 6, wl = tid & 63;
  wms[tid] = wm[tid];
  __syncthreads();
  const float* xi = x + (size_t)img * IMG_ + h * 64;
  double a0 = 0.0, a1 = 0.0, a2 = 0.0, a3 = 0.0;
#pragma unroll 4
  for (int i = 0; i < 16; ++i) {
#pragma unroll
    for (int u = 0; u < 4; ++u) {
      int c = (i * 4 + u) * 4 + wv;
      float v = xi[(size_t)c * HW_ + wl];
      lds[wl * 260 + c] = f2bf(v);
      double p = (double)v * (double)wms[c];
      if (u == 0) a0 += p;
      else if (u == 1) a1 += p;
      else if (u == 2) a2 += p;
      else a3 += p;
    }
  }
  sums[wv][wl] = (a0 + a1) + (a2 + a3);
  __syncthreads();
  short* Xpi = Xp + (size_t)img * PADIMG_ + ((h + 1) * 66 + 1) * 256;
#pragma unroll
  for (int j = 0; j < 16; ++j) {
    int w = j * 4 + wv;
    int c4 = wl * 4;
    uint2 d = *(const uint2*)&lds[w * 260 + c4];
    *(uint2*)&Xpi[(size_t)w * 256 + c4] = d;
  }
  if (wv == 0) {
    double t = sums[0][wl] + sums[1][wl] + sums[2][wl] + sums[3][wl] +
               (double)bm[0];
    mask[img * HW_ + h * 64 + wl] = (t > 0.0) ? 1 : 0;
  }
}

__global__ __launch_bounds__(256) void dilate_kernel(
    const unsigned char* __restrict__ mask, unsigned char* __restrict__ md) {
  int pix = blockIdx.x * 256 + threadIdx.x;
  int n = pix >> 12;
  int hw = pix & (HW_ - 1);
  int h = hw >> 6, w = hw & 63;
  int m = 0;
  for (int dy = -1; dy <= 1; dy++) {
    int hh = h + dy;
    if (hh < 0 || hh >= H_) continue;
    for (int dx = -1; dx <= 1; dx++) {
      int ww = w + dx;
      if (ww < 0 || ww >= W_) continue;
      m |= mask[n * HW_ + hh * W_ + ww];
    }
  }
  md[pix] = (unsigned char)m;
}

// ---------------------------------------------------------------------------
// Weight transform: Wt[t][kc][k][c16] = bf16(w[k][kc*16+c16][t])
// Layout so a conv wave's a-frag pair (64 lanes x 16B) is one contiguous,
// fully-coalesced 1KB global load: lane(ln31,kh) reads 16B at
// ((t*16+kc)*256 + k0 + ln31)*32B + kh*16B.
// ---------------------------------------------------------------------------
__global__ __launch_bounds__(256) void wt_kernel(
    const float* __restrict__ w1, const float* __restrict__ w2,
    short* __restrict__ Wt1, short* __restrict__ Wt2) {
  const int k = blockIdx.x, c = threadIdx.x;
  const float* src = blockIdx.y ? w2 : w1;
  short* dst = blockIdx.y ? Wt2 : Wt1;
  const float* s = src + ((size_t)k * 256 + c) * 9;
  const int kc = c >> 4, ce = c & 15;
#pragma unroll
  for (int t = 0; t < 9; ++t)
    dst[(((size_t)t * 16 + kc) * 256 + k) * 16 + ce] = (short)f2bf(s[t]);
}

// ---------------------------------------------------------------------------
// Zero the padded halo (rows 0,65; cols 0,65) of Xp and Hp.
// ---------------------------------------------------------------------------
__global__ __launch_bounds__(128) void halo_zero(short* __restrict__ Xp,
                                                 short* __restrict__ Hp) {
  int p = blockIdx.x;  // 0..259 halo pixel id
  int r, c;
  if (p < 66) { r = 0; c = p; }
  else if (p < 132) { r = 65; c = p - 66; }
  else if (p < 196) { r = p - 131; c = 0; }
  else { r = p - 195; c = 65; }
  short* buf = blockIdx.z ? Hp : Xp;
  unsigned int* d = (unsigned int*)(buf + (size_t)blockIdx.y * PADIMG_ +
                                    (size_t)(r * 66 + c) * 256);
  d[threadIdx.x] = 0u;
}

// ---------------------------------------------------------------------------
// Implicit-GEMM 3x3 conv, v3 (counted-vmcnt pipeline, W in registers).
// Tile: 64 out-ch x 512 px (8 rows x 64 cols), 4 waves, 2 blocks/CU.
// MFMA 32x32x16 bf16, K-chunk = 16 in-ch (16 chunks), acc 2x4 f32x16.
// LDS 63360 B = 3 x 21120 B triple-buffered B tile only (W never staged):
//   B[buf][khalf][660 slots][8ch x 2B]  -> conflict-free ds_read_b128.
// W frags: re-layout'd Wt gives coalesced 1KB L2 loads; tap t+1's pair is
// prefetched into regs during tap t's MFMAs (latency hidden by 8 MFMAs).
// Pipeline (T3/T4): stage B(kk+2) issued at END of compute kk; the FIFO
// order {..., W(kk+1,t0), B(kk+2)} means the compiler's counted W-waits
// retire B(kk+1) mid-compute (tap 1), so the kk boundary is a bare
// s_barrier -- NO vmcnt drain on the critical path (the round-1 stall).
// T5: setprio(1) around each 8-MFMA cluster (2 indep blocks/CU = diversity).
// EPI 0: dstH[padded NHWC] = g ? relu(acc) : 0        (g = dilated mask)
// EPI 1: dstF[NCHW fp32]   = xres + (g ? relu(acc):0) (g = std mask)
// ---------------------------------------------------------------------------
#define BBUF 10560  // shorts per B k-chunk buffer (2 K-halves x 660 x 8)

__device__ __forceinline__ void stage_B(short* sm, int buf, const short* Xb,
                                        int ko, int wave, int lane) {
  short* Bd = sm + buf * BBUF;
  // 22 insts (11 per K-half; inst i<10 covers slots 64i..64i+63, inst 10
  // covers 596..659 overlapping inst 9 with identical data). Waves 2,3 dup
  // inst 21 (same bytes -> benign) so all waves issue 6 (vmcnt symmetric).
#pragma unroll
  for (int q = 0; q < 6; ++q) {
    int n = wave + 4 * q;
    if (n > 21) n = 21;
    const int h = (n >= 11) ? 1 : 0;
    const int i = n - h * 11;
    const int row0 = (i < 10) ? i * 64 : 596;
    gld_lds16(Xb + (size_t)(row0 + lane) * 256 + ko + h * 8,
              Bd + h * 5280 + row0 * 8);
  }
}

template <int EPI>
__global__ __launch_bounds__(256, 2) void conv_mfma(
    const short* __restrict__ src, const short* __restrict__ Wt,
    const unsigned char* __restrict__ gate, const float* __restrict__ xres,
    short* __restrict__ dstH, float* __restrict__ dstF, int swz) {
  __shared__ __align__(16) short sm[3 * BBUF];  // 63360 B -> 2 blocks/CU

  const int tid = threadIdx.x;
  const int lane = tid & 63, wave = tid >> 6;
  const int ln31 = lane & 31, kh = lane >> 5;

  // Block decode; swizzled path groups the 4 ch-sibling blocks on one XCD.
  int bx, by, bz;
  {
    int d = blockIdx.x + 4 * (blockIdx.y + 8 * blockIdx.z);
    if (swz) {
      int k = d & 7, j = d >> 3;
      bx = j & 3;
      by = (j >> 2) & 7;
      bz = ((j >> 5) << 3) + k;
    } else {
      bx = blockIdx.x;
      by = blockIdx.y;
      bz = blockIdx.z;
    }
  }
  const int ch0 = bx * 64;
  const int h0 = by * 8;
  const int img = bz;

  const short* Xb = src + (size_t)img * PADIMG_ + (size_t)(h0 * 66) * 256;
  // Per-lane W base: element ((tkc)*256 + ch0 + i*32 + ln31)*16 + kh*8
  const short* WL = Wt + ((size_t)(ch0 + ln31)) * 16 + kh * 8;

  f32x16 acc[2][4];
#pragma unroll
  for (int i = 0; i < 2; ++i)
#pragma unroll
    for (int j = 0; j < 4; ++j)
#pragma unroll
      for (int e = 0; e < 16; ++e) acc[i][j][e] = 0.f;

  // Prologue: B(0), W(kk=0,t=0), B(1); retire B(0)+W, keep B(1) in flight.
  stage_B(sm, 0, Xb, 0, wave, lane);
  bf16x8 wa0 = *(const bf16x8*)(WL);
  bf16x8 wa1 = *(const bf16x8*)(WL + 512);
  stage_B(sm, 1, Xb, 16, wave, lane);
  asm volatile("s_waitcnt vmcnt(6)\n\ts_barrier" ::: "memory");

  int c0 = 0, c1 = 1, c2 = 2;
  for (int kk = 0; kk < 16; ++kk) {
    const short* Bth = sm + c0 * BBUF + kh * 5280 + (wave * 132 + ln31) * 8;
#pragma unroll
    for (int t = 0; t < 9; ++t) {
      // Prefetch next tap's W pair (t=8 -> (kk+1, tap0); kk=15 tail lands
      // in-bounds inside Wt's t=1 region and is never consumed).
      const int ntkc = (t < 8) ? ((t + 1) * 16 + kk) : (kk + 1);
      bf16x8 na0 = *(const bf16x8*)(WL + (size_t)ntkc * 4096);
      bf16x8 na1 = *(const bf16x8*)(WL + (size_t)ntkc * 4096 + 512);
      const int dy = t / 3, dx = t % 3;
      bf16x8 b[4];
#pragma unroll
      for (int j = 0; j < 4; ++j) {
        const int off = (((j >> 1) + dy) * 66 + (j & 1) * 32 + dx) * 8;
        b[j] = *(const bf16x8*)(Bth + off);
      }
      __builtin_amdgcn_s_setprio(1);
#pragma unroll
      for (int j = 0; j < 4; ++j) {
        acc[0][j] = __builtin_amdgcn_mfma_f32_32x32x16_bf16(wa0, b[j],
                                                            acc[0][j], 0, 0, 0);
        acc[1][j] = __builtin_amdgcn_mfma_f32_32x32x16_bf16(wa1, b[j],
                                                            acc[1][j], 0, 0, 0);
      }
      __builtin_amdgcn_s_setprio(0);
      wa0 = na0;
      wa1 = na1;
    }
    // Issue next-next B stage AFTER all of this kk's W loads so FIFO order
    // keeps it in flight across the boundary (drained by tap-1's W-wait of
    // kk+1, i.e. mid-compute). Target buffer c2 is idle this kk and next.
    if (kk < 14) stage_B(sm, c2, Xb, (kk + 2) * 16, wave, lane);
    if (kk < 15) asm volatile("s_barrier" ::: "memory");
    const int tmp = c0;
    c0 = c1;
    c1 = c2;
    c2 = tmp;
  }

  // Epilogue. 32x32 D layout: col(pixel)=lane&31, row(ch)=(reg&3)+8*(reg>>2)
  // +4*(lane>>5)  => reg group rg gives 4 consecutive channels.
  const int rb = h0 + wave * 2;
#pragma unroll
  for (int j = 0; j < 4; ++j) {
    const int r = rb + (j >> 1);
    const int col = (j & 1) * 32 + ln31;
    const int pidx = r * 64 + col;
    const unsigned char g = gate[img * HW_ + pidx];
#pragma unroll
    for (int i = 0; i < 2; ++i) {
      const f32x16 v = acc[i][j];
#pragma unroll
      for (int rg = 0; rg < 4; ++rg) {
        const int ch = ch0 + i * 32 + rg * 8 + kh * 4;
        float e0 = g ? fmaxf(v[rg * 4 + 0], 0.f) : 0.f;
        float e1 = g ? fmaxf(v[rg * 4 + 1], 0.f) : 0.f;
        float e2 = g ? fmaxf(v[rg * 4 + 2], 0.f) : 0.f;
        float e3 = g ? fmaxf(v[rg * 4 + 3], 0.f) : 0.f;
        if (EPI == 0) {
          uint2 u;
          u.x = (unsigned int)f2bf(e0) | ((unsigned int)f2bf(e1) << 16);
          u.y = (unsigned int)f2bf(e2) | ((unsigned int)f2bf(e3) << 16);
          short* dp = dstH + (size_t)img * PADIMG_ +
                      ((size_t)((r + 1) * 66 + (col + 1))) * 256 + ch;
          *(uint2*)dp = u;
        } else {
          size_t o = (size_t)img * IMG_ + (size_t)ch * HW_ + pidx;
          dstF[o] = xres[o] + e0;
          dstF[o + HW_] = xres[o + HW_] + e1;
          dstF[o + 2 * HW_] = xres[o + 2 * HW_] + e2;
          dstF[o + 3 * HW_] = xres[o + 3 * HW_] + e3;
        }
      }
    }
  }
}

// ---------------------------------------------------------------------------
extern "C" void kernel_launch(void* const* d_in, const int* in_sizes, int n_in,
                              void* d_out, int out_size, void* d_ws,
                              size_t ws_size, hipStream_t stream) {
  const float* x = (const float*)d_in[0];
  const float* w1 = (const float*)d_in[1];
  const float* w2 = (const float*)d_in[2];
  const float* wmask = (const float*)d_in[3];
  const float* bmask = (const float*)d_in[4];
  float* out = (float*)d_out;

  char* ws = (char*)d_ws;
  unsigned char* mask = (unsigned char*)ws;          // 64 KB
  unsigned char* md = (unsigned char*)(ws + 65536);  // 64 KB
  short* Wt1 = (short*)(ws + 131072);                // 1.125 MiB
  short* Wt2 = Wt1 + WT_ELEMS_;                      // 1.125 MiB
  short* Xp = (short*)(ws + 2490368);

  const size_t fixed = 2490368;
  const size_t tailpad = 32768;  // safety pad past last image
  const size_t per_img = 2 * (size_t)PADIMG_ * 2;  // Xp + Hp bytes per image
  int B = (ws_size > fixed + tailpad)
              ? (int)((ws_size - fixed - tailpad) / per_img) : 0;
  if (B > N_) B = N_;
  if (B < 1) B = 1;
  short* Hp = Xp + (size_t)B * PADIMG_;

  wt_kernel<<<dim3(256, 2), 256, 0, stream>>>(w1, w2, Wt1, Wt2);
  halo_zero<<<dim3(260, B, 2), 128, 0, stream>>>(Xp, Hp);

  for (int n0 = 0; n0 < N_; n0 += B) {
    const int nb = (N_ - n0 < B) ? (N_ - n0) : B;
    const int swz = (nb % 8 == 0) ? 1 : 0;
    xpadmask_kernel<<<dim3(64, nb), 256, 0, stream>>>(
        x + (size_t)n0 * IMG_, wmask, bmask, Xp, mask + n0 * HW_);
    dilate_kernel<<<nb * HW_ / 256, 256, 0, stream>>>(mask + n0 * HW_,
                                                      md + n0 * HW_);
    conv_mfma<0><<<dim3(4, 8, nb), 256, 0, stream>>>(
        Xp, Wt1, md + n0 * HW_, nullptr, Hp, nullptr, swz);
    conv_mfma<1><<<dim3(4, 8, nb), 256, 0, stream>>>(
        Hp, Wt2, mask + n0 * HW_, x + (size_t)n0 * IMG_, nullptr,
        out + (size_t)n0 * IMG_, swz);
  }
}